// Round 1
// baseline (265.518 us; speedup 1.0000x reference)
//
#include <hip/hip_runtime.h>

// ColorQuantizer: out[b,c,h,w] = palette[argmin_i dist(processed(x[b,:,h,w]), palette_i)][c]
// processed = relu(x@W1 + b1) @ W2 + b2   (all fp32, replicate reference op order)

#define PV(v) ((float)(v)/255.0f*2.0f-1.0f)
#define ROWF(r,g,c) {PV(r), PV(g), PV(c)}

// Runtime-indexed palette table (global .rodata) for the final gather.
__device__ const float PALG[16][3] = {
  ROWF(0,0,0),       ROWF(255,255,255), ROWF(255,0,0),     ROWF(0,255,0),
  ROWF(0,0,255),     ROWF(255,255,0),   ROWF(255,0,255),   ROWF(0,255,255),
  ROWF(128,128,128), ROWF(128,0,0),     ROWF(0,128,0),     ROWF(0,0,128),
  ROWF(128,128,0),   ROWF(128,0,128),   ROWF(0,128,128),   ROWF(192,192,192)
};

// Compile-time palette for the unrolled distance loop (folds to immediates).
constexpr int COLI[16][3] = {
  {0,0,0},{255,255,255},{255,0,0},{0,255,0},{0,0,255},{255,255,0},
  {255,0,255},{0,255,255},{128,128,128},{128,0,0},{0,128,0},{0,0,128},
  {128,128,0},{128,0,128},{0,128,128},{192,192,192}
};
constexpr float PVF(int v){ return (float)v/255.0f*2.0f-1.0f; }
constexpr float PXc(int i){ return PVF(COLI[i][0]); }
constexpr float PYc(int i){ return PVF(COLI[i][1]); }
constexpr float PZc(int i){ return PVF(COLI[i][2]); }
// sum(PALETTE*PALETTE, axis=-1) with the reference's reduce order: (x*x + y*y) + z*z
constexpr float PSQc(int i){ return (PXc(i)*PXc(i) + PYc(i)*PYc(i)) + PZc(i)*PZc(i); }

constexpr int HW    = 512*512;   // per-channel plane
constexpr int PXT   = 8;         // pixels per thread (2x float4)
constexpr int BLOCK = 256;

__global__ __launch_bounds__(BLOCK) void cq_kernel(
    const float* __restrict__ x,  const float* __restrict__ W1g,
    const float* __restrict__ b1g, const float* __restrict__ W2g,
    const float* __restrict__ b2g, float* __restrict__ out)
{
#pragma clang fp contract(off)
    __shared__ float sW1[96];  // W1[3][32] row-major
    __shared__ float sb1[32];
    __shared__ float sW2[96];  // W2[32][3] row-major
    __shared__ float sb2[3];

    const int t = threadIdx.x;
    if      (t < 96)  sW1[t]       = W1g[t];
    else if (t < 128) sb1[t-96]    = b1g[t-96];
    else if (t < 224) sW2[t-128]   = W2g[t-128];
    else if (t < 227) sb2[t-224]   = b2g[t-224];
    __syncthreads();

    const int pix = (blockIdx.x * BLOCK + t) * PXT;   // < 2^23, int is fine
    const int img = pix >> 18;                        // HW = 2^18
    const int hw  = pix & (HW - 1);
    const size_t base = (size_t)img * (size_t)(3*HW) + (size_t)hw;

    float X0[PXT], X1[PXT], X2[PXT];
    {
        float4 a0 = *(const float4*)(x + base);
        float4 a1 = *(const float4*)(x + base + 4);
        float4 c0 = *(const float4*)(x + base + HW);
        float4 c1 = *(const float4*)(x + base + HW + 4);
        float4 e0 = *(const float4*)(x + base + 2*HW);
        float4 e1 = *(const float4*)(x + base + 2*HW + 4);
        X0[0]=a0.x; X0[1]=a0.y; X0[2]=a0.z; X0[3]=a0.w;
        X0[4]=a1.x; X0[5]=a1.y; X0[6]=a1.z; X0[7]=a1.w;
        X1[0]=c0.x; X1[1]=c0.y; X1[2]=c0.z; X1[3]=c0.w;
        X1[4]=c1.x; X1[5]=c1.y; X1[6]=c1.z; X1[7]=c1.w;
        X2[0]=e0.x; X2[1]=e0.y; X2[2]=e0.z; X2[3]=e0.w;
        X2[4]=e1.x; X2[5]=e1.y; X2[6]=e1.z; X2[7]=e1.w;
    }

    // processed accumulators; dot runs from 0 so fma(h,u,0) == h*u exactly
    float P0[PXT], P1[PXT], P2[PXT];
#pragma unroll
    for (int k = 0; k < PXT; ++k) { P0[k]=0.0f; P1[k]=0.0f; P2[k]=0.0f; }

    // Fused MLP: hidden_j = relu((x0*w0 fma x1*w1 fma x2*w2) + b1_j); P_c += h*W2[j][c]
#pragma unroll
    for (int j = 0; j < 32; ++j) {
        const float w0 = sW1[j], w1 = sW1[32+j], w2 = sW1[64+j];
        const float bb = sb1[j];
        const float u0 = sW2[3*j], u1 = sW2[3*j+1], u2 = sW2[3*j+2];
#pragma unroll
        for (int k = 0; k < PXT; ++k) {
            float h = __builtin_fmaf(X2[k], w2, __builtin_fmaf(X1[k], w1, X0[k]*w0));
            h = h + bb;
            h = fmaxf(h, 0.0f);
            P0[k] = __builtin_fmaf(h, u0, P0[k]);
            P1[k] = __builtin_fmaf(h, u1, P1[k]);
            P2[k] = __builtin_fmaf(h, u2, P2[k]);
        }
    }

    int best[PXT];
#pragma unroll
    for (int k = 0; k < PXT; ++k) {
        const float p0 = P0[k] + sb2[0];
        const float p1 = P1[k] + sb2[1];
        const float p2 = P2[k] + sb2[2];
        const float psq = (p0*p0 + p1*p1) + p2*p2;  // reference reduce order
        float bd = 3.4e38f;
        int   bi = 0;
#pragma unroll
        for (int i = 0; i < 16; ++i) {
            float dot = __builtin_fmaf(p2, PZc(i), __builtin_fmaf(p1, PYc(i), p0*PXc(i)));
            float sq  = (psq - 2.0f*dot) + PSQc(i);     // (psq - 2*dot) + palsq
            float d   = sqrtf(fmaxf(sq, 0.0f));         // correctly-rounded, as numpy
            if (d < bd) { bd = d; bi = i; }             // first-occurrence argmin
        }
        best[k] = bi;
    }

    float* op = out + base;   // output has the same [b][c][hw] layout
    float4 o;
    o = make_float4(PALG[best[0]][0], PALG[best[1]][0], PALG[best[2]][0], PALG[best[3]][0]);
    *(float4*)(op) = o;
    o = make_float4(PALG[best[4]][0], PALG[best[5]][0], PALG[best[6]][0], PALG[best[7]][0]);
    *(float4*)(op + 4) = o;
    o = make_float4(PALG[best[0]][1], PALG[best[1]][1], PALG[best[2]][1], PALG[best[3]][1]);
    *(float4*)(op + HW) = o;
    o = make_float4(PALG[best[4]][1], PALG[best[5]][1], PALG[best[6]][1], PALG[best[7]][1]);
    *(float4*)(op + HW + 4) = o;
    o = make_float4(PALG[best[0]][2], PALG[best[1]][2], PALG[best[2]][2], PALG[best[3]][2]);
    *(float4*)(op + 2*HW) = o;
    o = make_float4(PALG[best[4]][2], PALG[best[5]][2], PALG[best[6]][2], PALG[best[7]][2]);
    *(float4*)(op + 2*HW + 4) = o;
}

extern "C" void kernel_launch(void* const* d_in, const int* in_sizes, int n_in,
                              void* d_out, int out_size, void* d_ws, size_t ws_size,
                              hipStream_t stream) {
    const float* x  = (const float*)d_in[0];
    const float* W1 = (const float*)d_in[1];
    const float* b1 = (const float*)d_in[2];
    const float* W2 = (const float*)d_in[3];
    const float* b2 = (const float*)d_in[4];
    float* outp = (float*)d_out;

    constexpr int NPIX = 32 * HW;                    // 8,388,608
    constexpr int GRID = NPIX / (BLOCK * PXT);       // 4096 blocks, exact
    hipLaunchKernelGGL(cq_kernel, dim3(GRID), dim3(BLOCK), 0, stream,
                       x, W1, b1, W2, b2, outp);
}